// Round 20
// baseline (89.819 us; speedup 1.0000x reference)
//
#include <hip/hip_runtime.h>

// CLM_26594437496868: co-attention (dual-softmax) + conv3x3 + BN + LeakyReLU
// b=4, c=64, h=w=64, hw=4096.
//
// R20: in-order-issue pipelining in attn. Waves issue in order, so R17's
// QK->exp->PV per half stalled exp on its own QK burst. Reorder per pair:
// QK(A) -> QK(B) -> exp(A) -> PV(A) -> exp(B) -> PV(B): exp(A) VALU overlaps
// QK(B) matrix-pipe drain; exp(B) overlaps PV(A). To fit ~124 live VGPRs
// under the (512,4) 128 cap, l moves off the MFMA pipe: scalar in-lane
// lsum (lane's 16 s-values share q-row=lr) + final xor16/32 shuffles;
// MFMA/pair 72->64. Rest identical to R19 (67.88us best).

typedef short bf16x8 __attribute__((ext_vector_type(8)));
typedef float f32x4 __attribute__((ext_vector_type(4)));
typedef unsigned int u32x4 __attribute__((ext_vector_type(4)));
typedef unsigned short ushort_t;
typedef ushort_t ushort8 __attribute__((ext_vector_type(8)));

#define HW 4096
#define NC 64
#define NB 4
#define RT_L2E 1.2011224087864498f   // sqrt(log2 e); (a*RT)*(b*RT) = a*b*log2e

#define GLB(p) ((const __attribute__((address_space(1))) unsigned int*)(p))
#define LDSP(p) ((__attribute__((address_space(3))) unsigned int*)(p))

__device__ __forceinline__ ushort_t f2bf(float f) {
  unsigned u = __builtin_bit_cast(unsigned, f);
  unsigned r = u + 0x7FFFu + ((u >> 16) & 1u);
  return (ushort_t)(r >> 16);
}

__device__ __forceinline__ float bf2f(ushort_t u) {
  unsigned v = ((unsigned)u) << 16;
  return __builtin_bit_cast(float, v);
}

__device__ __forceinline__ float fast_exp2(float x) {
#if __has_builtin(__builtin_amdgcn_exp2f)
  return __builtin_amdgcn_exp2f(x);
#else
  return exp2f(x);
#endif
}

__device__ __forceinline__ unsigned cvt_pk_bf16(float lo, float hi) {
  unsigned r;
  asm("v_cvt_pk_bf16_f32 %0, %1, %2" : "=v"(r) : "v"(lo), "v"(hi));
  return r;
}

// ---------------------------------------------------------------- prep ----
// grid 512 = 4 b x 128 chunks of 32 pos. t: g = t>>5 (8 ch / 8 outs), p = t&31.
// Emits: exlT_s/qT_s bf16 [b][pos][64ch] scaled by sqrt(log2e) (Q AND K roles);
//        q_tl/ex_tl bf16 tiled [b][kvblk][64ch][64 sigma-perm kv] (V);
//        exq bf16 [b][pos][64ch] = ex + q;
//        w9f bf16 [9][64o][64c] (conv weights, built by thread-ids < 36864).
__global__ __launch_bounds__(256) void prep_kernel(
    const float* __restrict__ ex, const float* __restrict__ q,
    const float* __restrict__ Wl, const float* __restrict__ Wc,
    ushort_t* __restrict__ exlT_s, ushort_t* __restrict__ qT_s,
    ushort_t* __restrict__ q_tl, ushort_t* __restrict__ ex_tl,
    ushort_t* __restrict__ exq, ushort_t* __restrict__ w9f)
{
  __shared__ float exs[64][33];
  __shared__ float wls[64][64];

  const int t = threadIdx.x;
  const int b = blockIdx.x >> 7;
  const int chunk = blockIdx.x & 127;
  const int g = t >> 5;          // 0..7
  const int p = t & 31;
  const int pos = chunk * 32 + p;
  const int tile = pos >> 6;
  const int kv = pos & 63;
  // sigma^-1: kv -> stored column, so MFMA k-position p reads V[sigma(p)].
  const int vcol = ((kv >> 5) << 5) + (((kv >> 2) & 3) << 3)
                 + (((kv >> 4) & 1) << 2) + (kv & 3);

  // conv weight re-layout (independent side-job for low thread-ids)
  {
    int widx = blockIdx.x * 256 + t;
    if (widx < 36864) {
      int o   = widx / 576;
      int rem = widx - o * 576;
      int c   = rem / 9;
      int tap = rem - c * 9;
      w9f[tap * 4096 + o * 64 + c] = f2bf(Wc[widx]);
    }
  }

  const float* exb = ex + (size_t)b * NC * HW;
  const float* qb  = q  + (size_t)b * NC * HW;
  ushort_t* exlTsb = exlT_s+ (size_t)b * HW * NC;
  ushort_t* qTsb   = qT_s  + (size_t)b * HW * NC;
  ushort_t* exqb   = exq   + (size_t)b * HW * NC;
  ushort_t* qtlb   = q_tl  + (size_t)b * HW * NC + (size_t)tile * 4096 + vcol;
  ushort_t* etlb   = ex_tl + (size_t)b * HW * NC + (size_t)tile * 4096 + vcol;

#pragma unroll
  for (int it = 0; it < 16; ++it) {
    int idx = it * 256 + t;
    wls[idx >> 6][idx & 63] = Wl[idx];
  }

  ushort8 qhs, eqh;
#pragma unroll
  for (int j = 0; j < 8; ++j) {
    int c = g * 8 + j;
    float ev = exb[c * HW + pos];
    exs[c][p] = ev;
    etlb[c * 64] = f2bf(ev);
    float qv = qb[c * HW + pos];
    qtlb[c * 64] = f2bf(qv);
    qhs[j] = f2bf(qv * RT_L2E);
    eqh[j] = f2bf(ev + qv);
  }
  *(ushort8*)(qTsb + (size_t)pos * NC + g * 8) = qhs;
  *(ushort8*)(exqb + (size_t)pos * NC + g * 8) = eqh;
  __syncthreads();

  // exl: out-channels g*8..g*8+8 for pos
  float acc[8];
#pragma unroll
  for (int oo = 0; oo < 8; ++oo) acc[oo] = 0.f;
  for (int c = 0; c < 64; ++c) {
    float xv = exs[c][p];
#pragma unroll
    for (int oo = 0; oo < 8; ++oo)
      acc[oo] += wls[g * 8 + oo][c] * xv;
  }
  {
    ushort8 hs;
#pragma unroll
    for (int oo = 0; oo < 8; ++oo) hs[oo] = f2bf(acc[oo] * RT_L2E);
    *(ushort8*)(exlTsb + (size_t)pos * NC + g * 8) = hs;
  }
}

// ---------------------------------------------------------------- attn ----
// grid: 128*S = 2 pass x 4 b x 16 qb(256 rows) x S; 512 threads = 8 waves,
// each wave TWO 16-row q-tiles. LDS: 4-phase K/V (64KB), XOR-swizzled,
// 2 kv-tiles per barrier. Issue order per pair: QK(A),QK(B),exp(A),PV(A),
// exp(B),PV(B) -> exp VALU overlaps matrix-pipe drain. l via scalar lsum.
__global__ __launch_bounds__(512, 4) void attn_kernel(
    const ushort_t* __restrict__ exlT_s, const ushort_t* __restrict__ qT_s,
    const ushort_t* __restrict__ q_tl, const ushort_t* __restrict__ ex_tl,
    ushort_t* __restrict__ Opart, float* __restrict__ lpart, int ss)
{
  __shared__ char smem[65536];  // [4][K 8KB | V 8KB]

  const int gid  = blockIdx.x;
  const int S    = 1 << ss;
  const int kvs  = gid & (S - 1);
  const int qb   = (gid >> ss) & 15;
  const int b    = (gid >> (ss + 4)) & 3;
  const int pass = gid >> (ss + 6);
  const int w    = threadIdx.x >> 6;     // 0..7
  const int lane = threadIdx.x & 63;
  const int lr = lane & 15, lg = lane >> 4;
  const int qrow0 = qb * 256 + w * 32;   // wave covers [qrow0, qrow0+32)

  const ushort_t* QT = (pass ? qT_s : exlT_s) + (size_t)b * HW * NC;
  const ushort_t* KT = (pass ? exlT_s : qT_s) + (size_t)b * HW * NC;
  const ushort_t* VT = (pass ? ex_tl : q_tl) + (size_t)b * HW * NC;

  bf16x8 aq0[2], aq1[2];
  {
    const ushort_t* qp0 = QT + (size_t)(qrow0 + lr) * NC + lg * 8;
    aq0[0] = *(const bf16x8*)(qp0);
    aq0[1] = *(const bf16x8*)(qp0 + 32);
    const ushort_t* qp1 = QT + (size_t)(qrow0 + 16 + lr) * NC + lg * 8;
    aq1[0] = *(const bf16x8*)(qp1);
    aq1[1] = *(const bf16x8*)(qp1 + 32);
  }

  f32x4 O0[4], O1[4];
  float lsum0 = 0.f, lsum1 = 0.f;
#pragma unroll
  for (int t = 0; t < 4; ++t) {
    O0[t] = (f32x4){0.f, 0.f, 0.f, 0.f};
    O1[t] = (f32x4){0.f, 0.f, 0.f, 0.f};
  }

  const int niter = 64 >> ss;
  const int kv0 = kvs * niter;

  // 8 waves: wave w stages bytes [w*1024, w*1024+1024) of each 8KB buffer.
  const int db0 = w * 1024 + (lane << 4);
#define STAGE(phase, kvb)                                                      \
  {                                                                            \
    char* Kl = smem + (phase) * 16384;                                         \
    char* Vl = Kl + 8192;                                                      \
    const char* kg = (const char*)(KT + (size_t)(kvb) * 64 * NC);              \
    const char* vg = (const char*)(VT + (size_t)(kvb) * 4096);                 \
    int swz = db0 ^ (((db0 >> 7) & 7) << 4);                                   \
    __builtin_amdgcn_global_load_lds(GLB(kg + swz),                            \
                                     LDSP(Kl + w * 1024), 16, 0, 0);           \
    __builtin_amdgcn_global_load_lds(GLB(vg + swz),                            \
                                     LDSP(Vl + w * 1024), 16, 0, 0);           \
  }

  STAGE(0, kv0);
  STAGE(1, kv0 + 1);
  __syncthreads();

  int pair = 0;   // active phase pair: phases {2*pair, 2*pair+1}
  for (int i = 0; i < niter; i += 2) {
    if (i + 2 < niter) {
      const int np = (pair ^ 1) * 2;
      STAGE(np, kv0 + i + 2);
      if (i + 3 < niter) STAGE(np + 1, kv0 + i + 3);
    }

    const int cswz = (lr & 7) << 4;   // (row&7)<<4 with row = t*16+lr
    const char* KlA = smem + (pair * 2) * 16384;
    const char* VlA = KlA + 8192;
    const char* KlB = KlA + 16384;
    const char* VlB = KlB + 8192;

    // ---- QK for BOTH halves, issued back-to-back (matrix pipe fills) ----
    f32x4 sA0[4], sA1[4], sB0[4], sB1[4];
#pragma unroll
    for (int t = 0; t < 4; ++t) {
      sA0[t] = (f32x4){0.f, 0.f, 0.f, 0.f};
      sA1[t] = (f32x4){0.f, 0.f, 0.f, 0.f};
      sB0[t] = (f32x4){0.f, 0.f, 0.f, 0.f};
      sB1[t] = (f32x4){0.f, 0.f, 0.f, 0.f};
    }
    __builtin_amdgcn_s_setprio(1);
#pragma unroll
    for (int ks = 0; ks < 2; ++ks)
#pragma unroll
      for (int t = 0; t < 4; ++t) {
        bf16x8 kf = *(const bf16x8*)(KlA + (t * 16 + lr) * 128
                                     + ((ks * 64 + lg * 16) ^ cswz));
        sA0[t] = __builtin_amdgcn_mfma_f32_16x16x32_bf16(kf, aq0[ks], sA0[t], 0, 0, 0);
        sA1[t] = __builtin_amdgcn_mfma_f32_16x16x32_bf16(kf, aq1[ks], sA1[t], 0, 0, 0);
      }
#pragma unroll
    for (int ks = 0; ks < 2; ++ks)
#pragma unroll
      for (int t = 0; t < 4; ++t) {
        bf16x8 kf = *(const bf16x8*)(KlB + (t * 16 + lr) * 128
                                     + ((ks * 64 + lg * 16) ^ cswz));
        sB0[t] = __builtin_amdgcn_mfma_f32_16x16x32_bf16(kf, aq0[ks], sB0[t], 0, 0, 0);
        sB1[t] = __builtin_amdgcn_mfma_f32_16x16x32_bf16(kf, aq1[ks], sB1[t], 0, 0, 0);
      }
    __builtin_amdgcn_s_setprio(0);

    // ---- exp+pack half A (VALU; overlaps QK(B) matrix drain) ----
    unsigned int paA0[2][4], paA1[2][4];
#pragma unroll
    for (int ks = 0; ks < 2; ++ks)
#pragma unroll
      for (int hf = 0; hf < 2; ++hf) {
        const int t = ks * 2 + hf;
        float a0 = fast_exp2(sA0[t][0]);
        float a1 = fast_exp2(sA0[t][1]);
        float a2 = fast_exp2(sA0[t][2]);
        float a3 = fast_exp2(sA0[t][3]);
        lsum0 += (a0 + a1) + (a2 + a3);
        paA0[ks][hf * 2]     = cvt_pk_bf16(a0, a1);
        paA0[ks][hf * 2 + 1] = cvt_pk_bf16(a2, a3);
        float c0 = fast_exp2(sA1[t][0]);
        float c1 = fast_exp2(sA1[t][1]);
        float c2 = fast_exp2(sA1[t][2]);
        float c3 = fast_exp2(sA1[t][3]);
        lsum1 += (c0 + c1) + (c2 + c3);
        paA1[ks][hf * 2]     = cvt_pk_bf16(c0, c1);
        paA1[ks][hf * 2 + 1] = cvt_pk_bf16(c2, c3);
      }

    // ---- PV half A ----
    __builtin_amdgcn_s_setprio(1);
#pragma unroll
    for (int ks = 0; ks < 2; ++ks) {
      u32x4 pv0 = {paA0[ks][0], paA0[ks][1], paA0[ks][2], paA0[ks][3]};
      u32x4 pv1 = {paA1[ks][0], paA1[ks][1], paA1[ks][2], paA1[ks][3]};
      bf16x8 paf0 = __builtin_bit_cast(bf16x8, pv0);
      bf16x8 paf1 = __builtin_bit_cast(bf16x8, pv1);
#pragma unroll
      for (int t = 0; t < 4; ++t) {
        bf16x8 vf = *(const bf16x8*)(VlA + (t * 16 + lr) * 128
                                     + ((ks * 64 + lg * 16) ^ cswz));
        O0[t] = __builtin_amdgcn_mfma_f32_16x16x32_bf16(paf0, vf, O0[t], 0, 0, 0);
        O1[t] = __builtin_amdgcn_mfma_f32_16x16x32_bf16(paf1, vf, O1[t], 0, 0, 0);
      }
    }
    __builtin_amdgcn_s_setprio(0);

    // ---- exp+pack half B (VALU; overlaps PV(A) matrix drain) ----
    unsigned int paB0[2][4], paB1[2][4];
#pragma unroll
    for (int ks = 0; ks < 2; ++ks)
#pragma unroll
      for (int hf = 0; hf < 2; ++hf) {
        const int t = ks * 2 + hf;
        float a0 = fast_exp2(sB0[t][0]);
        float a1 = fast_exp2(sB0[t][1]);
        float a2 = fast_exp2(sB0[t][2]);
        float a3 = fast_exp2(sB0[t][3]);
        lsum0 += (a0 + a1) + (a2 + a3);
        paB0[ks][hf * 2]     = cvt_pk_bf16(a0, a1);
        paB0[ks][hf * 2 + 1] = cvt_pk_bf16(a2, a3);
        float c0 = fast_exp2(sB1[t][0]);
        float c1 = fast_exp2(sB1[t][1]);
        float c2 = fast_exp2(sB1[t][2]);
        float c3 = fast_exp2(sB1[t][3]);
        lsum1 += (c0 + c1) + (c2 + c3);
        paB1[ks][hf * 2]     = cvt_pk_bf16(c0, c1);
        paB1[ks][hf * 2 + 1] = cvt_pk_bf16(c2, c3);
      }

    // ---- PV half B ----
    __builtin_amdgcn_s_setprio(1);
#pragma unroll
    for (int ks = 0; ks < 2; ++ks) {
      u32x4 pv0 = {paB0[ks][0], paB0[ks][1], paB0[ks][2], paB0[ks][3]};
      u32x4 pv1 = {paB1[ks][0], paB1[ks][1], paB1[ks][2], paB1[ks][3]};
      bf16x8 paf0 = __builtin_bit_cast(bf16x8, pv0);
      bf16x8 paf1 = __builtin_bit_cast(bf16x8, pv1);
#pragma unroll
      for (int t = 0; t < 4; ++t) {
        bf16x8 vf = *(const bf16x8*)(VlB + (t * 16 + lr) * 128
                                     + ((ks * 64 + lg * 16) ^ cswz));
        O0[t] = __builtin_amdgcn_mfma_f32_16x16x32_bf16(paf0, vf, O0[t], 0, 0, 0);
        O1[t] = __builtin_amdgcn_mfma_f32_16x16x32_bf16(paf1, vf, O1[t], 0, 0, 0);
      }
    }
    __builtin_amdgcn_s_setprio(0);

    __syncthreads();   // drains staging; releases consumed pair
    pair ^= 1;
  }

  // lane (lr,lg) holds partial l for q-row lr; reduce over the 4 lg groups.
  lsum0 += __shfl_xor(lsum0, 16);
  lsum0 += __shfl_xor(lsum0, 32);
  lsum1 += __shfl_xor(lsum1, 16);
  lsum1 += __shfl_xor(lsum1, 32);

  ushort_t* Ob = Opart + ((size_t)((pass * 4 + b) * S + kvs)) * (HW * NC);
  float* lp = lpart + ((size_t)((pass * 4 + b) * S + kvs)) * HW;
#pragma unroll
  for (int t = 0; t < 4; ++t)
#pragma unroll
    for (int r = 0; r < 4; ++r) {
      Ob[(size_t)(qrow0 + lg * 4 + r) * NC + t * 16 + lr] = f2bf(O0[t][r]);
      Ob[(size_t)(qrow0 + 16 + lg * 4 + r) * NC + t * 16 + lr] = f2bf(O1[t][r]);
    }
  if (lane < 16) {
    lp[qrow0 + lane] = lsum0;
    lp[qrow0 + 16 + lane] = lsum1;
  }
#undef STAGE
}

// --------------------------------------------------------------- merge ----
// xconv[b][h][w+1][ch] (bf16, w-padded 66 slots, zero side columns) =
//   exq + sum_pass (sum_s Opart_bf16) / (sum_s lpart)    [linv inlined]
__global__ __launch_bounds__(256) void merge_kernel(
    const ushort_t* __restrict__ Opart, const float* __restrict__ lpart,
    const ushort_t* __restrict__ exq, ushort_t* __restrict__ xconv, int S)
{
  const int idx = blockIdx.x * 256 + threadIdx.x;   // 131072 total
  const int c8  = (idx & 7) * 8;
  const int pos = (idx >> 3) & 4095;
  const int b   = idx >> 15;
  const int h   = pos >> 6;
  const int w   = pos & 63;

  float acc[8];
  {
    ushort8 e = *(const ushort8*)(exq + ((size_t)b * HW + pos) * NC + c8);
#pragma unroll
    for (int j = 0; j < 8; ++j) acc[j] = bf2f(e[j]);
  }

#pragma unroll
  for (int pass = 0; pass < 2; ++pass) {
    const int pp = pass * 4 + b;
    const ushort_t* opb = Opart + (size_t)pp * S * (HW * NC)
                        + (size_t)pos * NC + c8;
    float os[8];
#pragma unroll
    for (int j = 0; j < 8; ++j) os[j] = 0.f;
    float ls = 0.f;
    for (int s = 0; s < S; ++s) {
      ushort8 v = *(const ushort8*)(opb + (size_t)s * (HW * NC));
#pragma unroll
      for (int j = 0; j < 8; ++j) os[j] += bf2f(v[j]);
      ls += lpart[(size_t)(pp * S + s) * HW + pos];
    }
    float inv = 1.0f / ls;
#pragma unroll
    for (int j = 0; j < 8; ++j) acc[j] += os[j] * inv;
  }

  ushort_t* row = xconv + ((size_t)(b * 64 + h) * 66) * NC;
  ushort8 outv;
#pragma unroll
  for (int j = 0; j < 8; ++j) outv[j] = f2bf(acc[j]);
  *(ushort8*)(row + (size_t)(w + 1) * NC + c8) = outv;

  ushort8 z = {0, 0, 0, 0, 0, 0, 0, 0};
  if (w == 0)  *(ushort8*)(row + c8) = z;                       // slot 0
  if (w == 63) *(ushort8*)(row + (size_t)65 * NC + c8) = z;     // slot 65
}

// ---------------------------------------------------------------- conv ----
// grid 256 = 4 b x 64 h. 4 waves; wave wv -> o-tile [wv*16, wv*16+16).
// LDS: x 3 rows x 66 w x 128B (25,344B, XOR-swizzled) + W9 bf16 72KB.
// 72 MFMA + 90 ds_read_b128 per wave. Epilogue: per-block partial stats
// (plain stores, NO atomics).
#define XSZ 25344
__global__ __launch_bounds__(256) void conv_kernel(
    const ushort_t* __restrict__ xconv, const ushort_t* __restrict__ w9f,
    float* __restrict__ y, float* __restrict__ pstats)
{
  __shared__ char smem[XSZ + 73728];
  const int t  = threadIdx.x;
  const int h  = blockIdx.x & 63;
  const int b  = blockIdx.x >> 6;
  const int wv = t >> 6;
  const int lane = t & 63;
  const int lr = lane & 15, lg = lane >> 4;

  // ---- stage W9 (72KB = 4608 chunks), pre-swizzled source ----
  {
    const char* wsrc = (const char*)w9f;
#pragma unroll
    for (int i = 0; i < 18; ++i) {
      int d = (i * 256 + t) * 16;
      int s = d ^ (((d >> 7) & 7) << 4);
      __builtin_amdgcn_global_load_lds(GLB(wsrc + s),
          LDSP(smem + XSZ + (i * 256 + wv * 64) * 16), 16, 0, 0);
    }
  }

  // ---- stage x: 3 rows of 66 w x 128B = 528 chunks each ----
#pragma unroll
  for (int ky = 0; ky < 3; ++ky) {
    const int hs = h + ky - 1;
    char* dst0 = smem + ky * 8448;
    if (hs >= 0 && hs < 64) {
      const char* src = (const char*)(xconv + (size_t)(b * 64 + hs) * 66 * NC);
#pragma unroll
      for (int i = 0; i < 2; ++i) {
        int d = (i * 256 + t) * 16;
        int s = d ^ (((d >> 7) & 7) << 4);
        __builtin_amdgcn_global_load_lds(GLB(src + s),
            LDSP(dst0 + (i * 256 + wv * 64) * 16), 16, 0, 0);
      }
      if (t < 16) {
        int d = (512 + t) * 16;
        int s = d ^ (((d >> 7) & 7) << 4);
        __builtin_amdgcn_global_load_lds(GLB(src + s),
            LDSP(dst0 + 512 * 16), 16, 0, 0);
      }
    } else {
      u32x4 z = {0, 0, 0, 0};
#pragma unroll
      for (int i = 0; i < 2; ++i)
        *(u32x4*)(dst0 + (i * 256 + t) * 16) = z;
      if (t < 16) *(u32x4*)(dst0 + (512 + t) * 16) = z;
    }
  }
  __syncthreads();

  const char* xls = smem;
  const char* wls = smem + XSZ;

  f32x4 O[4];
#pragma unroll
  for (int tt = 0; tt < 4; ++tt) O[tt] = (f32x4){0.f, 0.f, 0.f, 0.f};

  const int orow = wv * 16 + lr;
  const int oswz = (lr & 7) << 4;     // orow&7 == lr&7 (wv*16 ≡ 0 mod 8)

#pragma unroll
  for (int tap = 0; tap < 9; ++tap) {
    const int ky = tap / 3, kx = tap % 3;
    bf16x8 wa[2];
#pragma unroll
    for (int ks = 0; ks < 2; ++ks)
      wa[ks] = *(const bf16x8*)(wls + tap * 8192 + orow * 128
                                + (((ks * 4 + lg) << 4) ^ oswz));
#pragma unroll
    for (int tt = 0; tt < 4; ++tt) {
      const int row = tt * 16 + lr + kx;
      const int rswz = (row & 7) << 4;
#pragma unroll
      for (int ks = 0; ks < 2; ++ks) {
        bf16x8 bf = *(const bf16x8*)(xls + ky * 8448 + row * 128
                                     + (((ks * 4 + lg) << 4) ^ rswz));
        O[tt] = __builtin_amdgcn_mfma_f32_16x16x32_bf16(wa[ks], bf, O[tt], 0, 0, 0);
      }
    }
  }

  // ---- epilogue: y write + per-block partial stats (plain stores) ----
  float* ps = pstats + (size_t)blockIdx.x * 128;
#pragma unroll
  for (int r = 0; r < 4; ++r) {
    const int o = wv * 16 + lg * 4 + r;
    float s1 = 0.f, s2 = 0.f;
#pragma unroll
    for (int tt = 0; tt < 4; ++tt) {
      float v = O[tt][r];
      y[(size_t)(b * 64 + o) * HW + h * 64 + tt * 16 + lr] = v;
      s1 += v; s2 += v * v;
    }
    s1 += __shfl_xor(s1, 1); s1 += __shfl_xor(s1, 2);
    s1 += __shfl_xor(s1, 4); s1 += __shfl_xor(s1, 8);
    s2 += __shfl_xor(s2, 1); s2 += __shfl_xor(s2, 2);
    s2 += __shfl_xor(s2, 4); s2 += __shfl_xor(s2, 8);
    if (lr == 0) { ps[o] = s1; ps[64 + o] = s2; }
  }
}

// -------------------------------------------------------------- statred ---
// stats[i] = sum_{blk<256} pstats[blk][i], i in [0,128). 1 block x 128 thr.
__global__ __launch_bounds__(128) void statred_kernel(
    const float* __restrict__ pstats, float* __restrict__ stats)
{
  const int i = threadIdx.x;
  float s = 0.f;
  for (int k = 0; k < 256; ++k) s += pstats[k * 128 + i];
  stats[i] = s;
}

// ------------------------------------------------------------------ bn ----
__global__ __launch_bounds__(256) void bn_kernel(
    const float* __restrict__ y, const float* __restrict__ stats,
    const float* __restrict__ gamma, const float* __restrict__ beta,
    float* __restrict__ out)
{
  const int e = (blockIdx.x * 256 + threadIdx.x) * 4;
  const int o = (e >> 12) & 63;
  float mean = stats[o] * (1.f / 16384.f);
  float var  = stats[64 + o] * (1.f / 16384.f) - mean * mean;
  float g  = gamma[o] * rsqrtf(var + 1e-5f);
  float bt = beta[o] - mean * g;
  float4 v = *(const float4*)(y + e);
  float4 r;
  r.x = v.x * g + bt; r.x = r.x > 0.f ? r.x : 0.1f * r.x;
  r.y = v.y * g + bt; r.y = r.y > 0.f ? r.y : 0.1f * r.y;
  r.z = v.z * g + bt; r.z = r.z > 0.f ? r.z : 0.1f * r.z;
  r.w = v.w * g + bt; r.w = r.w > 0.f ? r.w : 0.1f * r.w;
  *(float4*)(out + e) = r;
}

// -------------------------------------------------------------- launch ----
extern "C" void kernel_launch(void* const* d_in, const int* in_sizes, int n_in,
                              void* d_out, int out_size, void* d_ws, size_t ws_size,
                              hipStream_t stream)
{
  const float* ex    = (const float*)d_in[0];
  const float* q     = (const float*)d_in[1];
  const float* Wl    = (const float*)d_in[2];
  const float* Wc    = (const float*)d_in[3];
  const float* gamma = (const float*)d_in[4];
  const float* beta  = (const float*)d_in[5];
  float* out = (float*)d_out;

  char* ws = (char*)d_ws;
  ushort_t* exlT_s = (ushort_t*)(ws);                   // 2 MB (dead after attn)
  ushort_t* qT_s   = (ushort_t*)(ws + (2u << 20));      // 2 MB (dead after attn)
  ushort_t* q_tl   = (ushort_t*)(ws + (4u << 20));      // 2 MB V tiles (perm)
  ushort_t* ex_tl  = (ushort_t*)(ws + (6u << 20));      // 2 MB V tiles (perm)
  ushort_t* exq    = (ushort_t*)(ws + (8u << 20));      // 2 MB bf16 ex+q [pos][ch]
  ushort_t* xconv  = (ushort_t*)(ws + (10u << 20));     // 2.06 MB bf16 padded
  float* stats  = (float*)(ws + (14u << 20));           // 512 B
  float* lpart  = (float*)(ws + (14u << 20) + 65536);   // <=512 KB
  float* pstats = (float*)(ws + (14u << 20) + 589824);  // 128 KB (256x128 f32)
  ushort_t* w9f = (ushort_t*)(ws + (14u << 20) + 786432); // 72 KB bf16 [9][o][c]
  ushort_t* Opart = (ushort_t*)(ws + (15u << 20));      // S*4 MB bf16
  float* yBuf  = (float*)(ws);                          // 4 MB, aliases exlT_s/qT_s

  // kv-split factor from scratch budget: need 15MB + S*4MB
  int ss;
  if (ws_size >= (31u << 20)) ss = 2;
  else if (ws_size >= (23u << 20)) ss = 1;
  else ss = 0;
  const int S = 1 << ss;

  prep_kernel<<<512, 256, 0, stream>>>(ex, q, Wl, Wc, exlT_s, qT_s, q_tl, ex_tl,
                                       exq, w9f);
  attn_kernel<<<128 * S, 512, 0, stream>>>(exlT_s, qT_s, q_tl, ex_tl,
                                           Opart, lpart, ss);
  merge_kernel<<<512, 256, 0, stream>>>(Opart, lpart, exq, xconv, S);
  conv_kernel<<<256, 256, 0, stream>>>(xconv, w9f, yBuf, pstats);
  statred_kernel<<<1, 128, 0, stream>>>(pstats, stats);
  bn_kernel<<<1024, 256, 0, stream>>>(yBuf, stats, gamma, beta, out);
}

// Round 21
// 67.683 us; speedup vs baseline: 1.3271x; 1.3271x over previous
//
#include <hip/hip_runtime.h>

// CLM_26594437496868: co-attention (dual-softmax) + conv3x3 + BN + LeakyReLU
// b=4, c=64, h=w=64, hw=4096.
//
// R21: restore R19 exactly (67.88us best). R20's 4-live-S-tile reorder
// spilled (VGPR pinned at 64 by the allocator heuristic, FETCH 15->48MB,
// MfmaUtil 20%) -> third allocator-defeated restructure (R1, R3, R20).
// Config: R16 attn (2 q-tiles/wave, 4-phase LDS, setprio, ones-MFMA l);
// R15 conv (256 blk, 72 MFMA/wave, pstats/statred, no atomics);
// prep-built w9f; inlined-linv merge.

typedef short bf16x8 __attribute__((ext_vector_type(8)));
typedef float f32x4 __attribute__((ext_vector_type(4)));
typedef unsigned int u32x4 __attribute__((ext_vector_type(4)));
typedef unsigned short ushort_t;
typedef ushort_t ushort8 __attribute__((ext_vector_type(8)));

#define HW 4096
#define NC 64
#define NB 4
#define RT_L2E 1.2011224087864498f   // sqrt(log2 e); (a*RT)*(b*RT) = a*b*log2e

#define GLB(p) ((const __attribute__((address_space(1))) unsigned int*)(p))
#define LDSP(p) ((__attribute__((address_space(3))) unsigned int*)(p))

__device__ __forceinline__ ushort_t f2bf(float f) {
  unsigned u = __builtin_bit_cast(unsigned, f);
  unsigned r = u + 0x7FFFu + ((u >> 16) & 1u);
  return (ushort_t)(r >> 16);
}

__device__ __forceinline__ float bf2f(ushort_t u) {
  unsigned v = ((unsigned)u) << 16;
  return __builtin_bit_cast(float, v);
}

__device__ __forceinline__ float fast_exp2(float x) {
#if __has_builtin(__builtin_amdgcn_exp2f)
  return __builtin_amdgcn_exp2f(x);
#else
  return exp2f(x);
#endif
}

__device__ __forceinline__ unsigned cvt_pk_bf16(float lo, float hi) {
  unsigned r;
  asm("v_cvt_pk_bf16_f32 %0, %1, %2" : "=v"(r) : "v"(lo), "v"(hi));
  return r;
}

// ---------------------------------------------------------------- prep ----
// grid 512 = 4 b x 128 chunks of 32 pos. t: g = t>>5 (8 ch / 8 outs), p = t&31.
// Emits: exlT_s/qT_s bf16 [b][pos][64ch] scaled by sqrt(log2e) (Q AND K roles);
//        q_tl/ex_tl bf16 tiled [b][kvblk][64ch][64 sigma-perm kv] (V);
//        exq bf16 [b][pos][64ch] = ex + q;
//        w9f bf16 [9][64o][64c] (conv weights, built by thread-ids < 36864).
__global__ __launch_bounds__(256) void prep_kernel(
    const float* __restrict__ ex, const float* __restrict__ q,
    const float* __restrict__ Wl, const float* __restrict__ Wc,
    ushort_t* __restrict__ exlT_s, ushort_t* __restrict__ qT_s,
    ushort_t* __restrict__ q_tl, ushort_t* __restrict__ ex_tl,
    ushort_t* __restrict__ exq, ushort_t* __restrict__ w9f)
{
  __shared__ float exs[64][33];
  __shared__ float wls[64][64];

  const int t = threadIdx.x;
  const int b = blockIdx.x >> 7;
  const int chunk = blockIdx.x & 127;
  const int g = t >> 5;          // 0..7
  const int p = t & 31;
  const int pos = chunk * 32 + p;
  const int tile = pos >> 6;
  const int kv = pos & 63;
  // sigma^-1: kv -> stored column, so MFMA k-position p reads V[sigma(p)].
  const int vcol = ((kv >> 5) << 5) + (((kv >> 2) & 3) << 3)
                 + (((kv >> 4) & 1) << 2) + (kv & 3);

  // conv weight re-layout (independent side-job for low thread-ids)
  {
    int widx = blockIdx.x * 256 + t;
    if (widx < 36864) {
      int o   = widx / 576;
      int rem = widx - o * 576;
      int c   = rem / 9;
      int tap = rem - c * 9;
      w9f[tap * 4096 + o * 64 + c] = f2bf(Wc[widx]);
    }
  }

  const float* exb = ex + (size_t)b * NC * HW;
  const float* qb  = q  + (size_t)b * NC * HW;
  ushort_t* exlTsb = exlT_s+ (size_t)b * HW * NC;
  ushort_t* qTsb   = qT_s  + (size_t)b * HW * NC;
  ushort_t* exqb   = exq   + (size_t)b * HW * NC;
  ushort_t* qtlb   = q_tl  + (size_t)b * HW * NC + (size_t)tile * 4096 + vcol;
  ushort_t* etlb   = ex_tl + (size_t)b * HW * NC + (size_t)tile * 4096 + vcol;

#pragma unroll
  for (int it = 0; it < 16; ++it) {
    int idx = it * 256 + t;
    wls[idx >> 6][idx & 63] = Wl[idx];
  }

  ushort8 qhs, eqh;
#pragma unroll
  for (int j = 0; j < 8; ++j) {
    int c = g * 8 + j;
    float ev = exb[c * HW + pos];
    exs[c][p] = ev;
    etlb[c * 64] = f2bf(ev);
    float qv = qb[c * HW + pos];
    qtlb[c * 64] = f2bf(qv);
    qhs[j] = f2bf(qv * RT_L2E);
    eqh[j] = f2bf(ev + qv);
  }
  *(ushort8*)(qTsb + (size_t)pos * NC + g * 8) = qhs;
  *(ushort8*)(exqb + (size_t)pos * NC + g * 8) = eqh;
  __syncthreads();

  // exl: out-channels g*8..g*8+8 for pos
  float acc[8];
#pragma unroll
  for (int oo = 0; oo < 8; ++oo) acc[oo] = 0.f;
  for (int c = 0; c < 64; ++c) {
    float xv = exs[c][p];
#pragma unroll
    for (int oo = 0; oo < 8; ++oo)
      acc[oo] += wls[g * 8 + oo][c] * xv;
  }
  {
    ushort8 hs;
#pragma unroll
    for (int oo = 0; oo < 8; ++oo) hs[oo] = f2bf(acc[oo] * RT_L2E);
    *(ushort8*)(exlTsb + (size_t)pos * NC + g * 8) = hs;
  }
}

// ---------------------------------------------------------------- attn ----
// grid: 128*S = 2 pass x 4 b x 16 qb(256 rows) x S; 512 threads = 8 waves,
// each wave TWO 16-row q-tiles sharing every kf/vf ds_read. LDS: 4-phase
// K(8KB)+V(8KB) buffers (64KB), XOR-swizzled; 2 kv-tiles per barrier.
// P in registers; l via ones-MFMA; setprio(1) around MFMA clusters.
__global__ __launch_bounds__(512, 4) void attn_kernel(
    const ushort_t* __restrict__ exlT_s, const ushort_t* __restrict__ qT_s,
    const ushort_t* __restrict__ q_tl, const ushort_t* __restrict__ ex_tl,
    ushort_t* __restrict__ Opart, float* __restrict__ lpart, int ss)
{
  __shared__ char smem[65536];  // [4][K 8KB | V 8KB]

  const int gid  = blockIdx.x;
  const int S    = 1 << ss;
  const int kvs  = gid & (S - 1);
  const int qb   = (gid >> ss) & 15;
  const int b    = (gid >> (ss + 4)) & 3;
  const int pass = gid >> (ss + 6);
  const int w    = threadIdx.x >> 6;     // 0..7
  const int lane = threadIdx.x & 63;
  const int lr = lane & 15, lg = lane >> 4;
  const int qrow0 = qb * 256 + w * 32;   // wave covers [qrow0, qrow0+32)

  const ushort_t* QT = (pass ? qT_s : exlT_s) + (size_t)b * HW * NC;
  const ushort_t* KT = (pass ? exlT_s : qT_s) + (size_t)b * HW * NC;
  const ushort_t* VT = (pass ? ex_tl : q_tl) + (size_t)b * HW * NC;

  bf16x8 aq0[2], aq1[2];
  {
    const ushort_t* qp0 = QT + (size_t)(qrow0 + lr) * NC + lg * 8;
    aq0[0] = *(const bf16x8*)(qp0);
    aq0[1] = *(const bf16x8*)(qp0 + 32);
    const ushort_t* qp1 = QT + (size_t)(qrow0 + 16 + lr) * NC + lg * 8;
    aq1[0] = *(const bf16x8*)(qp1);
    aq1[1] = *(const bf16x8*)(qp1 + 32);
  }

  const u32x4 onesu = {0x3F803F80u, 0x3F803F80u, 0x3F803F80u, 0x3F803F80u};
  const bf16x8 vones = __builtin_bit_cast(bf16x8, onesu);

  f32x4 O0[4], O1[4];
  f32x4 lacc0 = (f32x4){0.f, 0.f, 0.f, 0.f};
  f32x4 lacc1 = (f32x4){0.f, 0.f, 0.f, 0.f};
#pragma unroll
  for (int t = 0; t < 4; ++t) {
    O0[t] = (f32x4){0.f, 0.f, 0.f, 0.f};
    O1[t] = (f32x4){0.f, 0.f, 0.f, 0.f};
  }

  const int niter = 64 >> ss;
  const int kv0 = kvs * niter;

  // 8 waves: wave w stages bytes [w*1024, w*1024+1024) of each 8KB buffer.
  const int db0 = w * 1024 + (lane << 4);
#define STAGE(phase, kvb)                                                      \
  {                                                                            \
    char* Kl = smem + (phase) * 16384;                                         \
    char* Vl = Kl + 8192;                                                      \
    const char* kg = (const char*)(KT + (size_t)(kvb) * 64 * NC);              \
    const char* vg = (const char*)(VT + (size_t)(kvb) * 4096);                 \
    int swz = db0 ^ (((db0 >> 7) & 7) << 4);                                   \
    __builtin_amdgcn_global_load_lds(GLB(kg + swz),                            \
                                     LDSP(Kl + w * 1024), 16, 0, 0);           \
    __builtin_amdgcn_global_load_lds(GLB(vg + swz),                            \
                                     LDSP(Vl + w * 1024), 16, 0, 0);           \
  }

  STAGE(0, kv0);
  STAGE(1, kv0 + 1);
  __syncthreads();

  int pair = 0;   // active phase pair: phases {2*pair, 2*pair+1}
  for (int i = 0; i < niter; i += 2) {
    if (i + 2 < niter) {
      const int np = (pair ^ 1) * 2;
      STAGE(np, kv0 + i + 2);
      if (i + 3 < niter) STAGE(np + 1, kv0 + i + 3);
    }

    const int cswz = (lr & 7) << 4;   // (row&7)<<4 with row = t*16+lr

#pragma unroll
    for (int half = 0; half < 2; ++half) {
      const char* Kl = smem + (pair * 2 + half) * 16384;
      const char* Vl = Kl + 8192;

      // ---- S^T = K Q^T for both q-tiles; each kf read feeds two MFMAs ----
      f32x4 s0[4], s1[4];
#pragma unroll
      for (int t = 0; t < 4; ++t) {
        s0[t] = (f32x4){0.f, 0.f, 0.f, 0.f};
        s1[t] = (f32x4){0.f, 0.f, 0.f, 0.f};
      }
      __builtin_amdgcn_s_setprio(1);
#pragma unroll
      for (int ks = 0; ks < 2; ++ks)
#pragma unroll
        for (int t = 0; t < 4; ++t) {
          bf16x8 kf = *(const bf16x8*)(Kl + (t * 16 + lr) * 128
                                       + ((ks * 64 + lg * 16) ^ cswz));
          s0[t] = __builtin_amdgcn_mfma_f32_16x16x32_bf16(kf, aq0[ks], s0[t], 0, 0, 0);
          s1[t] = __builtin_amdgcn_mfma_f32_16x16x32_bf16(kf, aq1[ks], s1[t], 0, 0, 0);
        }
      __builtin_amdgcn_s_setprio(0);

      // ---- p = exp2(s); cvt_pk packs into PV A-fragments (both tiles) ----
      unsigned int pa0[2][4], pa1[2][4];
#pragma unroll
      for (int ks = 0; ks < 2; ++ks)
#pragma unroll
        for (int hf = 0; hf < 2; ++hf) {
          const int t = ks * 2 + hf;
          float a0 = fast_exp2(s0[t][0]);
          float a1 = fast_exp2(s0[t][1]);
          float a2 = fast_exp2(s0[t][2]);
          float a3 = fast_exp2(s0[t][3]);
          pa0[ks][hf * 2]     = cvt_pk_bf16(a0, a1);
          pa0[ks][hf * 2 + 1] = cvt_pk_bf16(a2, a3);
          float c0 = fast_exp2(s1[t][0]);
          float c1 = fast_exp2(s1[t][1]);
          float c2 = fast_exp2(s1[t][2]);
          float c3 = fast_exp2(s1[t][3]);
          pa1[ks][hf * 2]     = cvt_pk_bf16(c0, c1);
          pa1[ks][hf * 2 + 1] = cvt_pk_bf16(c2, c3);
        }

      // ---- O += P V; l += P*ones; each vf read feeds two MFMAs ----
      __builtin_amdgcn_s_setprio(1);
#pragma unroll
      for (int ks = 0; ks < 2; ++ks) {
        u32x4 pv0 = {pa0[ks][0], pa0[ks][1], pa0[ks][2], pa0[ks][3]};
        u32x4 pv1 = {pa1[ks][0], pa1[ks][1], pa1[ks][2], pa1[ks][3]};
        bf16x8 paf0 = __builtin_bit_cast(bf16x8, pv0);
        bf16x8 paf1 = __builtin_bit_cast(bf16x8, pv1);
        lacc0 = __builtin_amdgcn_mfma_f32_16x16x32_bf16(paf0, vones, lacc0, 0, 0, 0);
        lacc1 = __builtin_amdgcn_mfma_f32_16x16x32_bf16(paf1, vones, lacc1, 0, 0, 0);
#pragma unroll
        for (int t = 0; t < 4; ++t) {
          bf16x8 vf = *(const bf16x8*)(Vl + (t * 16 + lr) * 128
                                       + ((ks * 64 + lg * 16) ^ cswz));
          O0[t] = __builtin_amdgcn_mfma_f32_16x16x32_bf16(paf0, vf, O0[t], 0, 0, 0);
          O1[t] = __builtin_amdgcn_mfma_f32_16x16x32_bf16(paf1, vf, O1[t], 0, 0, 0);
        }
      }
      __builtin_amdgcn_s_setprio(0);
    }

    __syncthreads();   // drains staging; releases consumed pair
    pair ^= 1;
  }

  ushort_t* Ob = Opart + ((size_t)((pass * 4 + b) * S + kvs)) * (HW * NC);
  float* lp = lpart + ((size_t)((pass * 4 + b) * S + kvs)) * HW;
#pragma unroll
  for (int t = 0; t < 4; ++t)
#pragma unroll
    for (int r = 0; r < 4; ++r) {
      Ob[(size_t)(qrow0 + lg * 4 + r) * NC + t * 16 + lr] = f2bf(O0[t][r]);
      Ob[(size_t)(qrow0 + 16 + lg * 4 + r) * NC + t * 16 + lr] = f2bf(O1[t][r]);
    }
  if (lr == 0) {
#pragma unroll
    for (int r = 0; r < 4; ++r) {
      lp[qrow0 + lg * 4 + r] = lacc0[r];
      lp[qrow0 + 16 + lg * 4 + r] = lacc1[r];
    }
  }
#undef STAGE
}

// --------------------------------------------------------------- merge ----
// xconv[b][h][w+1][ch] (bf16, w-padded 66 slots, zero side columns) =
//   exq + sum_pass (sum_s Opart_bf16) / (sum_s lpart)    [linv inlined]
__global__ __launch_bounds__(256) void merge_kernel(
    const ushort_t* __restrict__ Opart, const float* __restrict__ lpart,
    const ushort_t* __restrict__ exq, ushort_t* __restrict__ xconv, int S)
{
  const int idx = blockIdx.x * 256 + threadIdx.x;   // 131072 total
  const int c8  = (idx & 7) * 8;
  const int pos = (idx >> 3) & 4095;
  const int b   = idx >> 15;
  const int h   = pos >> 6;
  const int w   = pos & 63;

  float acc[8];
  {
    ushort8 e = *(const ushort8*)(exq + ((size_t)b * HW + pos) * NC + c8);
#pragma unroll
    for (int j = 0; j < 8; ++j) acc[j] = bf2f(e[j]);
  }

#pragma unroll
  for (int pass = 0; pass < 2; ++pass) {
    const int pp = pass * 4 + b;
    const ushort_t* opb = Opart + (size_t)pp * S * (HW * NC)
                        + (size_t)pos * NC + c8;
    float os[8];
#pragma unroll
    for (int j = 0; j < 8; ++j) os[j] = 0.f;
    float ls = 0.f;
    for (int s = 0; s < S; ++s) {
      ushort8 v = *(const ushort8*)(opb + (size_t)s * (HW * NC));
#pragma unroll
      for (int j = 0; j < 8; ++j) os[j] += bf2f(v[j]);
      ls += lpart[(size_t)(pp * S + s) * HW + pos];
    }
    float inv = 1.0f / ls;
#pragma unroll
    for (int j = 0; j < 8; ++j) acc[j] += os[j] * inv;
  }

  ushort_t* row = xconv + ((size_t)(b * 64 + h) * 66) * NC;
  ushort8 outv;
#pragma unroll
  for (int j = 0; j < 8; ++j) outv[j] = f2bf(acc[j]);
  *(ushort8*)(row + (size_t)(w + 1) * NC + c8) = outv;

  ushort8 z = {0, 0, 0, 0, 0, 0, 0, 0};
  if (w == 0)  *(ushort8*)(row + c8) = z;                       // slot 0
  if (w == 63) *(ushort8*)(row + (size_t)65 * NC + c8) = z;     // slot 65
}

// ---------------------------------------------------------------- conv ----
// grid 256 = 4 b x 64 h. 4 waves; wave wv -> o-tile [wv*16, wv*16+16).
// LDS: x 3 rows x 66 w x 128B (25,344B, XOR-swizzled) + W9 bf16 72KB.
// 72 MFMA + 90 ds_read_b128 per wave. Epilogue: per-block partial stats
// (plain stores, NO atomics).
#define XSZ 25344
__global__ __launch_bounds__(256) void conv_kernel(
    const ushort_t* __restrict__ xconv, const ushort_t* __restrict__ w9f,
    float* __restrict__ y, float* __restrict__ pstats)
{
  __shared__ char smem[XSZ + 73728];
  const int t  = threadIdx.x;
  const int h  = blockIdx.x & 63;
  const int b  = blockIdx.x >> 6;
  const int wv = t >> 6;
  const int lane = t & 63;
  const int lr = lane & 15, lg = lane >> 4;

  // ---- stage W9 (72KB = 4608 chunks), pre-swizzled source ----
  {
    const char* wsrc = (const char*)w9f;
#pragma unroll
    for (int i = 0; i < 18; ++i) {
      int d = (i * 256 + t) * 16;
      int s = d ^ (((d >> 7) & 7) << 4);
      __builtin_amdgcn_global_load_lds(GLB(wsrc + s),
          LDSP(smem + XSZ + (i * 256 + wv * 64) * 16), 16, 0, 0);
    }
  }

  // ---- stage x: 3 rows of 66 w x 128B = 528 chunks each ----
#pragma unroll
  for (int ky = 0; ky < 3; ++ky) {
    const int hs = h + ky - 1;
    char* dst0 = smem + ky * 8448;
    if (hs >= 0 && hs < 64) {
      const char* src = (const char*)(xconv + (size_t)(b * 64 + hs) * 66 * NC);
#pragma unroll
      for (int i = 0; i < 2; ++i) {
        int d = (i * 256 + t) * 16;
        int s = d ^ (((d >> 7) & 7) << 4);
        __builtin_amdgcn_global_load_lds(GLB(src + s),
            LDSP(dst0 + (i * 256 + wv * 64) * 16), 16, 0, 0);
      }
      if (t < 16) {
        int d = (512 + t) * 16;
        int s = d ^ (((d >> 7) & 7) << 4);
        __builtin_amdgcn_global_load_lds(GLB(src + s),
            LDSP(dst0 + 512 * 16), 16, 0, 0);
      }
    } else {
      u32x4 z = {0, 0, 0, 0};
#pragma unroll
      for (int i = 0; i < 2; ++i)
        *(u32x4*)(dst0 + (i * 256 + t) * 16) = z;
      if (t < 16) *(u32x4*)(dst0 + (512 + t) * 16) = z;
    }
  }
  __syncthreads();

  const char* xls = smem;
  const char* wls = smem + XSZ;

  f32x4 O[4];
#pragma unroll
  for (int tt = 0; tt < 4; ++tt) O[tt] = (f32x4){0.f, 0.f, 0.f, 0.f};

  const int orow = wv * 16 + lr;
  const int oswz = (lr & 7) << 4;     // orow&7 == lr&7 (wv*16 ≡ 0 mod 8)

#pragma unroll
  for (int tap = 0; tap < 9; ++tap) {
    const int ky = tap / 3, kx = tap % 3;
    bf16x8 wa[2];
#pragma unroll
    for (int ks = 0; ks < 2; ++ks)
      wa[ks] = *(const bf16x8*)(wls + tap * 8192 + orow * 128
                                + (((ks * 4 + lg) << 4) ^ oswz));
#pragma unroll
    for (int tt = 0; tt < 4; ++tt) {
      const int row = tt * 16 + lr + kx;
      const int rswz = (row & 7) << 4;
#pragma unroll
      for (int ks = 0; ks < 2; ++ks) {
        bf16x8 bf = *(const bf16x8*)(xls + ky * 8448 + row * 128
                                     + (((ks * 4 + lg) << 4) ^ rswz));
        O[tt] = __builtin_amdgcn_mfma_f32_16x16x32_bf16(wa[ks], bf, O[tt], 0, 0, 0);
      }
    }
  }

  // ---- epilogue: y write + per-block partial stats (plain stores) ----
  float* ps = pstats + (size_t)blockIdx.x * 128;
#pragma unroll
  for (int r = 0; r < 4; ++r) {
    const int o = wv * 16 + lg * 4 + r;
    float s1 = 0.f, s2 = 0.f;
#pragma unroll
    for (int tt = 0; tt < 4; ++tt) {
      float v = O[tt][r];
      y[(size_t)(b * 64 + o) * HW + h * 64 + tt * 16 + lr] = v;
      s1 += v; s2 += v * v;
    }
    s1 += __shfl_xor(s1, 1); s1 += __shfl_xor(s1, 2);
    s1 += __shfl_xor(s1, 4); s1 += __shfl_xor(s1, 8);
    s2 += __shfl_xor(s2, 1); s2 += __shfl_xor(s2, 2);
    s2 += __shfl_xor(s2, 4); s2 += __shfl_xor(s2, 8);
    if (lr == 0) { ps[o] = s1; ps[64 + o] = s2; }
  }
}

// -------------------------------------------------------------- statred ---
// stats[i] = sum_{blk<256} pstats[blk][i], i in [0,128). 1 block x 128 thr.
__global__ __launch_bounds__(128) void statred_kernel(
    const float* __restrict__ pstats, float* __restrict__ stats)
{
  const int i = threadIdx.x;
  float s = 0.f;
  for (int k = 0; k < 256; ++k) s += pstats[k * 128 + i];
  stats[i] = s;
}

// ------------------------------------------------------------------ bn ----
__global__ __launch_bounds__(256) void bn_kernel(
    const float* __restrict__ y, const float* __restrict__ stats,
    const float* __restrict__ gamma, const float* __restrict__ beta,
    float* __restrict__ out)
{
  const int e = (blockIdx.x * 256 + threadIdx.x) * 4;
  const int o = (e >> 12) & 63;
  float mean = stats[o] * (1.f / 16384.f);
  float var  = stats[64 + o] * (1.f / 16384.f) - mean * mean;
  float g  = gamma[o] * rsqrtf(var + 1e-5f);
  float bt = beta[o] - mean * g;
  float4 v = *(const float4*)(y + e);
  float4 r;
  r.x = v.x * g + bt; r.x = r.x > 0.f ? r.x : 0.1f * r.x;
  r.y = v.y * g + bt; r.y = r.y > 0.f ? r.y : 0.1f * r.y;
  r.z = v.z * g + bt; r.z = r.z > 0.f ? r.z : 0.1f * r.z;
  r.w = v.w * g + bt; r.w = r.w > 0.f ? r.w : 0.1f * r.w;
  *(float4*)(out + e) = r;
}

// -------------------------------------------------------------- launch ----
extern "C" void kernel_launch(void* const* d_in, const int* in_sizes, int n_in,
                              void* d_out, int out_size, void* d_ws, size_t ws_size,
                              hipStream_t stream)
{
  const float* ex    = (const float*)d_in[0];
  const float* q     = (const float*)d_in[1];
  const float* Wl    = (const float*)d_in[2];
  const float* Wc    = (const float*)d_in[3];
  const float* gamma = (const float*)d_in[4];
  const float* beta  = (const float*)d_in[5];
  float* out = (float*)d_out;

  char* ws = (char*)d_ws;
  ushort_t* exlT_s = (ushort_t*)(ws);                   // 2 MB (dead after attn)
  ushort_t* qT_s   = (ushort_t*)(ws + (2u << 20));      // 2 MB (dead after attn)
  ushort_t* q_tl   = (ushort_t*)(ws + (4u << 20));      // 2 MB V tiles (perm)
  ushort_t* ex_tl  = (ushort_t*)(ws + (6u << 20));      // 2 MB V tiles (perm)
  ushort_t* exq    = (ushort_t*)(ws + (8u << 20));      // 2 MB bf16 ex+q [pos][ch]
  ushort_t* xconv  = (ushort_t*)(ws + (10u << 20));     // 2.06 MB bf16 padded
  float* stats  = (float*)(ws + (14u << 20));           // 512 B
  float* lpart  = (float*)(ws + (14u << 20) + 65536);   // <=512 KB
  float* pstats = (float*)(ws + (14u << 20) + 589824);  // 128 KB (256x128 f32)
  ushort_t* w9f = (ushort_t*)(ws + (14u << 20) + 786432); // 72 KB bf16 [9][o][c]
  ushort_t* Opart = (ushort_t*)(ws + (15u << 20));      // S*4 MB bf16
  float* yBuf  = (float*)(ws);                          // 4 MB, aliases exlT_s/qT_s

  // kv-split factor from scratch budget: need 15MB + S*4MB
  int ss;
  if (ws_size >= (31u << 20)) ss = 2;
  else if (ws_size >= (23u << 20)) ss = 1;
  else ss = 0;
  const int S = 1 << ss;

  prep_kernel<<<512, 256, 0, stream>>>(ex, q, Wl, Wc, exlT_s, qT_s, q_tl, ex_tl,
                                       exq, w9f);
  attn_kernel<<<128 * S, 512, 0, stream>>>(exlT_s, qT_s, q_tl, ex_tl,
                                           Opart, lpart, ss);
  merge_kernel<<<512, 256, 0, stream>>>(Opart, lpart, exq, xconv, S);
  conv_kernel<<<256, 256, 0, stream>>>(xconv, w9f, yBuf, pstats);
  statred_kernel<<<1, 128, 0, stream>>>(pstats, stats);
  bn_kernel<<<1024, 256, 0, stream>>>(yBuf, stats, gamma, beta, out);
}